// Round 11
// baseline (325.651 us; speedup 1.0000x reference)
//
#include <hip/hip_runtime.h>

typedef short  s8v   __attribute__((ext_vector_type(8)));
typedef float  f32x4 __attribute__((ext_vector_type(4)));

#define SEQ 2048
#define WID 768

__device__ __forceinline__ unsigned fbits(float f) {
    union { float f; unsigned u; } v; v.f = f; return v.u;
}
__device__ __forceinline__ float bitsf(unsigned u) {
    union { unsigned u; float f; } v; v.u = u; return v.f;
}
__device__ __forceinline__ unsigned short f2b(float f) {
    unsigned u = fbits(f);
    return (unsigned short)((u + 0x7FFFu + ((u >> 16) & 1u)) >> 16);   // RNE
}
__device__ __forceinline__ unsigned packRNE(float a, float b) {
    unsigned ta = fbits(a) + 0x7FFFu + ((fbits(a) >> 16) & 1u);
    unsigned tb = fbits(b) + 0x7FFFu + ((fbits(b) >> 16) & 1u);
    return __builtin_amdgcn_perm(tb, ta, 0x07060302u);
}
__device__ __forceinline__ unsigned packTRUNC(float a, float b) {
    return __builtin_amdgcn_perm(fbits(b), fbits(a), 0x07060302u);
}
__device__ __forceinline__ f32x4 zero4() { f32x4 z = {0.f, 0.f, 0.f, 0.f}; return z; }

// ---------------------------------------------------------------------------
// kernel 1: mask->PM (blocks [0,256), 8 gids/block) + proj (blocks [256,768)).
// TWO stream operations total this round (was 3): tests the per-launch-
// overhead hypothesis (~26us/op) that the R8-R18 accounting implies.
//
// Proj = R18's verified v4 geometry (512 blocks x 512 thr, 32-row tiles,
// 2 blocks/CU) with B staged DIRECTLY from Wq/Wk/Wv (f32) via in-register
// packRNE -- bit-identical LDS image to the old WF DMA (same (ntg,h,lane,j)
// -> W_mat[kc*64+h*32+quad*8+j][(ntg&3)*16+c] mapping, same pack code), so
// the WF intermediate and the separate convert launch are eliminated.
// XCD-local: proj block p = blk-256 (256%8==0 -> runs on XCD p%8), batch
// bsw = p&7, 32-row tile tsw = p>>3.  Epilogue verbatim R18 (verified).
// ---------------------------------------------------------------------------
__global__ __launch_bounds__(512, 4) void mask_proj_kernel(
    const float* __restrict__ x, const int* __restrict__ mask,
    const float* __restrict__ Wq, const float* __restrict__ Wk, const float* __restrict__ Wv,
    const float* __restrict__ bq, const float* __restrict__ bk, const float* __restrict__ bv,
    unsigned short* __restrict__ QF, unsigned short* __restrict__ KF,
    unsigned short* __restrict__ VF, unsigned* __restrict__ PM)
{
    __shared__ unsigned short AB[2][14336];   // per buf: A shorts [0,2048), B [2048,14336)
    unsigned short (*St)[200] = (unsigned short(*)[200])AB;   // epilogue overlay (12.8KB, buf0)

    const int tid = threadIdx.x;
    const int wv = tid >> 6, lane = tid & 63, quad = lane >> 4, c = lane & 15;
    const int blk = blockIdx.x;

    if (blk < 256) {
        // ---- mask -> PM, swapped layout (verified R10 logic, 8 gids/block)
        const int gid = blk * 8 + wv;              // (qb32, kb), 0..2047
        const int qb = gid >> 5, kb = gid & 31;
        unsigned w = 0;
        #pragma unroll
        for (int mt = 0; mt < 2; ++mt) {
            const int q = qb * 32 + mt * 16 + c;
            #pragma unroll
            for (int i = 0; i < 4; ++i) {
                const int4 mm = *(const int4*)&mask[(size_t)q * SEQ + kb * 64 + quad * 16 + 4 * i];
                if (mm.x) w |= 1u << (mt * 16 + i * 4 + 0);
                if (mm.y) w |= 1u << (mt * 16 + i * 4 + 1);
                if (mm.z) w |= 1u << (mt * 16 + i * 4 + 2);
                if (mm.w) w |= 1u << (mt * 16 + i * 4 + 3);
            }
        }
        PM[(size_t)gid * 64 + lane] = w;
        return;
    }

    // ---- proj role
    const int p = blk - 256;
    const int rg = wv >> 2, cg = wv & 3;       // rg in {0,1}
    const int bsw = p & 7, tsw = p >> 3;       // batch, 32-row tile (XCD-local)
    const int kbt2 = bsw * 64 + tsw;           // global 32-row tile index
    const int kbt  = kbt2 >> 1, hb = kbt2 & 1; // 64-key KV tile, half
    const int g0r  = kbt2 * 2;                 // first rowgroup (16-row)

    float bias[3];
    #pragma unroll
    for (int nt = 0; nt < 3; ++nt) {
        int col = cg * 48 + nt * 16 + c;
        const float* B = (col < 64) ? bq : (col < 128) ? bk : bv;
        bias[nt] = B[col & 63];
    }

    // A staging: float4/thread, frag-tiled image (R13/R18-verified mapping)
    const int ach = tid >> 7;
    const int agl = ach >> 1, ah = ach & 1;
    const int al  = (tid >> 1) & 63;
    const int aj0 = (tid & 1) * 4;
    const float* xptr = x + (size_t)((g0r + agl) * 16 + (al & 15)) * WID
                          + ah * 32 + ((al >> 4) & 3) * 8 + aj0;

    // B staging: 3 chunks/thread (e = wv*3+r), 8 f32 loads each from W,
    // packRNE -> bit-identical image to the old WF DMA.
    float pB[3][8];
    auto loadB = [&](int kc) {
        #pragma unroll
        for (int r = 0; r < 3; ++r) {
            const int e = wv * 3 + r;          // 0..23: ntg = e>>1, half h
            const int ntg = e >> 1, h = e & 1;
            const int mat = ntg >> 2;
            const int col = (ntg & 3) * 16 + c;
            const int k0 = kc * 64 + h * 32 + quad * 8;
            const float* Wm = (mat == 0) ? Wq : (mat == 1) ? Wk : Wv;
            #pragma unroll
            for (int j = 0; j < 8; ++j) pB[r][j] = Wm[(size_t)(k0 + j) * 64 + col];
        }
    };
    auto storeB = [&](int b) {
        #pragma unroll
        for (int r = 0; r < 3; ++r) {
            const int e = wv * 3 + r;
            const int ntg = e >> 1, h = e & 1;
            uint4 w;
            w.x = packRNE(pB[r][0], pB[r][1]); w.y = packRNE(pB[r][2], pB[r][3]);
            w.z = packRNE(pB[r][4], pB[r][5]); w.w = packRNE(pB[r][6], pB[r][7]);
            *(uint4*)&AB[b][2048 + (ntg * 2 + h) * 512 + lane * 8] = w;
        }
    };
    auto stageA = [&](int b, float4 f) {
        uint2 w2;
        w2.x = packRNE(f.x, f.y);
        w2.y = packRNE(f.z, f.w);
        *(uint2*)&AB[b][(size_t)tid * 4] = w2;
    };

    f32x4 acc[3];
    #pragma unroll
    for (int nt = 0; nt < 3; ++nt) acc[nt] = zero4();

    {   // prologue: stage A(0)+B(0) -> buf0
        float4 f = *(const float4*)&xptr[0];
        loadB(0);
        stageA(0, f);
        storeB(0);
    }

    for (int kc = 0; kc < 12; ++kc) {
        const int b = kc & 1;
        __syncthreads();   // publish buf b; readers of b^1 finished
        float4 f;
        if (kc < 11) {
            f = *(const float4*)&xptr[(kc + 1) * 64];
            loadB(kc + 1);
        }

        s8v afr[2], bfr[3][2];
        #pragma unroll
        for (int h = 0; h < 2; ++h)
            afr[h] = *(const s8v*)&AB[b][(rg * 2 + h) * 512 + lane * 8];
        #pragma unroll
        for (int nt = 0; nt < 3; ++nt)
            #pragma unroll
            for (int h = 0; h < 2; ++h)
                bfr[nt][h] = *(const s8v*)&AB[b][2048 + ((cg * 3 + nt) * 2 + h) * 512 + lane * 8];
        #pragma unroll
        for (int h = 0; h < 2; ++h)
            #pragma unroll
            for (int nt = 0; nt < 3; ++nt)
                acc[nt] = __builtin_amdgcn_mfma_f32_16x16x32_bf16(
                    afr[h], bfr[nt][h], acc[nt], 0, 0, 0);

        if (kc < 11) { stageA(b ^ 1, f); storeB(b ^ 1); }
    }

    // ---- epilogue: bias + stage 32x192 bf16 tile (verbatim R18, verified)
    #pragma unroll
    for (int nt = 0; nt < 3; ++nt)
        #pragma unroll
        for (int i = 0; i < 4; ++i)
            St[rg * 16 + quad * 4 + i][cg * 48 + nt * 16 + c]
                = f2b(acc[nt][i] + bias[nt]);
    __syncthreads();

    if (tid < 256) {   // QF: g = tid>>7 (rowgroup), ks = (tid>>6)&1, l = tid&63
        const int g = tid >> 7, ks = (tid >> 6) & 1, l = tid & 63;
        uint4 v = *(uint4*)&St[g * 16 + (l & 15)][ks * 32 + (l >> 4) * 8];
        *(uint4*)&QF[(((size_t)(g0r + g)) * 2 + ks) * 512 + (size_t)l * 8] = v;
    } else {           // KF half-tile: keys [hb*32, hb*32+32)
        const int t2 = tid - 256;
        const int ksnt = t2 >> 5, idx = t2 & 31;
        const int ks = ksnt >> 2, nt = ksnt & 3;
        const int qd = idx >> 3, ci = idx & 7;
        const int l = qd * 16 + hb * 8 + ci;
        uint4 v = *(uint4*)&St[4 * ci + nt][64 + ks * 32 + qd * 8];
        *(uint4*)&KF[(((size_t)kbt * 8 + ksnt) * 64 + l) * 8] = v;
    }
    if (tid < 256) {   // VF half-tile (V transpose, permuted key axis)
        const int ksnt = tid >> 5, idx = tid & 31;
        const int ks = ksnt >> 2, nt = ksnt & 3;
        const int qd = hb * 2 + (idx >> 4), c2 = idx & 15;
        const int l = qd * 16 + c2;
        const int r0 = (idx >> 4) * 16 + ks * 8;
        const int d = 128 + nt * 16 + c2;
        unsigned short pp[8];
        #pragma unroll
        for (int s = 0; s < 8; ++s) pp[s] = St[r0 + s][d];
        uint4 w;
        w.x = (unsigned)pp[0] | ((unsigned)pp[1] << 16);
        w.y = (unsigned)pp[2] | ((unsigned)pp[3] << 16);
        w.z = (unsigned)pp[4] | ((unsigned)pp[5] << 16);
        w.w = (unsigned)pp[6] | ((unsigned)pp[7] << 16);
        *(uint4*)&VF[(((size_t)kbt * 8 + ksnt) * 64 + l) * 8] = w;
    }
}

// ---------------------------------------------------------------------------
// attn (verbatim R17, verified 47.0us, FROZEN): R12 geometry + batched loads
// with counted vmcnt + asm pins + raw v_exp_f32.
// ---------------------------------------------------------------------------
__global__ __launch_bounds__(1024, 4) void attn_kernel(
    const unsigned short* __restrict__ QF, const unsigned short* __restrict__ KF,
    const unsigned short* __restrict__ VF, const unsigned* __restrict__ PM,
    float* __restrict__ out)
{
    __shared__ float Obuf[64][68];             // 17.4KB merge buffer
    __shared__ float Lbuf[64];

    const int tid = threadIdx.x;
    const int wv = tid >> 6, lane = tid & 63, quad = lane >> 4, c = lane & 15;
    const int sl = wv & 3, qg = wv >> 2, mt = qg & 1;
    const int blk = blockIdx.x;
    const int bb = blk & 7, qt = blk >> 3;
    const size_t qrow0 = (size_t)bb * SEQ + qt * 64;

    if (tid < 64) Lbuf[tid] = 0.f;

    union Q8 { s8v v; unsigned w[4]; };
    Q8 qf[2];
    {
        const size_t qgrp = (size_t)bb * 128 + qt * 4 + qg;
        #pragma unroll
        for (int ks = 0; ks < 2; ++ks)
            qf[ks].v = *(const s8v*)&QF[(qgrp * 2 + ks) * 512 + (size_t)lane * 8];
    }

    f32x4 O[4];
    float lro0 = 0.f, lro1 = 0.f;
    #pragma unroll
    for (int nt = 0; nt < 4; ++nt) O[nt] = zero4();

    const unsigned* pmrow = PM + (size_t)((qt * 2 + (qg >> 1)) * 32 + sl * 8) * 64 + lane;

    #pragma unroll 1
    for (int kt = 0; kt < 8; ++kt) {
        const size_t kbg = (size_t)bb * 32 + sl * 8 + kt;
        const unsigned short* kb_ = KF + kbg * 4096 + (size_t)lane * 8;
        const unsigned short* vb_ = VF + kbg * 4096 + (size_t)lane * 8;

        const unsigned pmw = pmrow[(size_t)kt * 64];   // oldest outstanding

        // ---- issue ALL 16 fragment loads back-to-back (K first, V second)
        Q8 kf8[8], vf8[8];
        #pragma unroll
        for (int d = 0; d < 8; ++d) kf8[d].v = *(const s8v*)&kb_[(size_t)d * 512];
        #pragma unroll
        for (int d = 0; d < 8; ++d) vf8[d].v = *(const s8v*)&vb_[(size_t)d * 512];

        // ---- K (and pm) complete; V's 8 loads still in flight
        asm volatile("s_waitcnt vmcnt(8)" ::: "memory");
        #pragma unroll
        for (int d = 0; d < 8; ++d)
            #pragma unroll
            for (int j = 0; j < 4; ++j) asm volatile("" : "+v"(kf8[d].w[j]));
        __builtin_amdgcn_sched_barrier(0);

        // ---- S^T = K Q^T : lane (quad,c) gets S[q=c][key = 16*quad + 4*i + nt]
        f32x4 S[4];
        #pragma unroll
        for (int nt = 0; nt < 4; ++nt) S[nt] = zero4();
        #pragma unroll
        for (int ks = 0; ks < 2; ++ks)
            #pragma unroll
            for (int nt = 0; nt < 4; ++nt)
                S[nt] = __builtin_amdgcn_mfma_f32_16x16x32_bf16(kf8[ks * 4 + nt].v, qf[ks].v, S[nt], 0, 0, 0);

        // ---- fixed-shift softmax (raw v_exp_f32); V latency hides under this
        const unsigned pmh = pmw >> (mt * 16);
        float p[4][4];                              // p[nt][i] = key 16*quad+4*i+nt
        #pragma unroll
        for (int i = 0; i < 4; ++i)
            #pragma unroll
            for (int nt = 0; nt < 4; ++nt) {
                float e = __builtin_amdgcn_exp2f(
                    fmaf(S[nt][i], 0.18033688011112042f, -21.640425613334451f));
                p[nt][i] = ((pmh >> (i * 4 + nt)) & 1u) ? e : 0.f;
            }
        union { unsigned w[8]; s8v v[2]; } P;       // shorts = keys 16*quad+0..15
        #pragma unroll
        for (int j = 0; j < 8; ++j) {
            unsigned uu = packTRUNC(p[2 * (j & 1)][j >> 1], p[2 * (j & 1) + 1][j >> 1]);
            P.w[j] = uu;
            if (j & 1) lro1 += bitsf(uu << 16) + bitsf(uu & 0xFFFF0000u);
            else       lro0 += bitsf(uu << 16) + bitsf(uu & 0xFFFF0000u);
        }

        // ---- V complete; pin and run PV
        asm volatile("s_waitcnt vmcnt(0)" ::: "memory");
        #pragma unroll
        for (int d = 0; d < 8; ++d)
            #pragma unroll
            for (int j = 0; j < 4; ++j) asm volatile("" : "+v"(vf8[d].w[j]));
        __builtin_amdgcn_sched_barrier(0);

        #pragma unroll
        for (int ks = 0; ks < 2; ++ks)
            #pragma unroll
            for (int nt = 0; nt < 4; ++nt)
                O[nt] = __builtin_amdgcn_mfma_f32_16x16x32_bf16(P.v[ks], vf8[ks * 4 + nt].v, O[nt], 0, 0, 0);
    }

    // ---- merge 4 slices per q-group
    #pragma unroll
    for (int j = 0; j < 5; ++j) {
        int idx = tid + 1024 * j;
        if (idx < 64 * 68) ((float*)Obuf)[idx] = 0.f;
    }
    __syncthreads();

    {
        float l = lro0 + lro1;
        l += __shfl_xor(l, 16);
        l += __shfl_xor(l, 32);
        if (quad == 0) atomicAdd(&Lbuf[qg * 16 + c], l);
    }
    #pragma unroll
    for (int i = 0; i < 4; ++i)
        #pragma unroll
        for (int nt = 0; nt < 4; ++nt)
            atomicAdd(&Obuf[qg * 16 + quad * 4 + i][nt * 16 + c], O[nt][i]);
    __syncthreads();
    {
        const int r = tid >> 4, d4 = (tid & 15) * 4;
        const float invL = 1.0f / Lbuf[r];
        float4 v = *(float4*)&Obuf[r][d4];
        float4 o = make_float4(v.x * invL, v.y * invL, v.z * invL, v.w * invL);
        *(float4*)&out[(qrow0 + r) * 64 + d4] = o;
    }
}

extern "C" void kernel_launch(void* const* d_in, const int* in_sizes, int n_in,
                              void* d_out, int out_size, void* d_ws, size_t ws_size,
                              hipStream_t stream)
{
    const float* x    = (const float*)d_in[0];
    const float* Wq   = (const float*)d_in[1];
    const float* bq   = (const float*)d_in[2];
    const float* Wk   = (const float*)d_in[3];
    const float* bk   = (const float*)d_in[4];
    const float* Wv   = (const float*)d_in[5];
    const float* bv   = (const float*)d_in[6];
    const int*   mask = (const int*)d_in[7];
    float* out = (float*)d_out;

    // ws: QF/KF/VF 2MB each + PM 512KB  (WF eliminated)
    unsigned short* QF = (unsigned short*)d_ws;
    unsigned short* KF = QF + (size_t)16384 * 64;
    unsigned short* VF = KF + (size_t)16384 * 64;
    unsigned*       PM = (unsigned*)(VF + (size_t)16384 * 64);

    mask_proj_kernel<<<768, 512, 0, stream>>>(x, mask, Wq, Wk, Wv, bq, bk, bv,
                                              QF, KF, VF, PM);
    attn_kernel<<<256, 1024, 0, stream>>>(QF, KF, VF, PM, out);
}

// Round 12
// 159.883 us; speedup vs baseline: 2.0368x; 2.0368x over previous
//
#include <hip/hip_runtime.h>

typedef short  s8v   __attribute__((ext_vector_type(8)));
typedef float  f32x4 __attribute__((ext_vector_type(4)));

#define SEQ 2048
#define WID 768

__device__ __forceinline__ unsigned fbits(float f) {
    union { float f; unsigned u; } v; v.f = f; return v.u;
}
__device__ __forceinline__ float bitsf(unsigned u) {
    union { unsigned u; float f; } v; v.u = u; return v.f;
}
__device__ __forceinline__ unsigned short f2b(float f) {
    unsigned u = fbits(f);
    return (unsigned short)((u + 0x7FFFu + ((u >> 16) & 1u)) >> 16);   // RNE
}
__device__ __forceinline__ unsigned packRNE(float a, float b) {
    unsigned ta = fbits(a) + 0x7FFFu + ((fbits(a) >> 16) & 1u);
    unsigned tb = fbits(b) + 0x7FFFu + ((fbits(b) >> 16) & 1u);
    return __builtin_amdgcn_perm(tb, ta, 0x07060302u);
}
__device__ __forceinline__ unsigned packTRUNC(float a, float b) {
    return __builtin_amdgcn_perm(fbits(b), fbits(a), 0x07060302u);
}
__device__ __forceinline__ f32x4 zero4() { f32x4 z = {0.f, 0.f, 0.f, 0.f}; return z; }

// async global->LDS DMA, 16B/lane; global ptr includes lane offset, LDS base wave-uniform
__device__ __forceinline__ void async16(const unsigned short* g, unsigned short* l) {
    __builtin_amdgcn_global_load_lds(
        (const __attribute__((address_space(1))) unsigned int*)g,
        (__attribute__((address_space(3))) unsigned int*)l, 16, 0, 0);
}

// ---------------------------------------------------------------------------
// convert (verified R10): blocks [0,512): mask -> PM, swapped layout:
//   word at (gid=(qb,kb), lane=(quad,c)), bit (mt*16 + i*4 + nt) =
//     mask[qb*32 + mt*16 + c][kb*64 + quad*16 + i*4 + nt]
// blocks [512,584): W -> WF bf16 B-frag-tiled
// ---------------------------------------------------------------------------
__global__ __launch_bounds__(256) void convert_kernel(
    const int* __restrict__ mask,
    const float* __restrict__ Wq, const float* __restrict__ Wk, const float* __restrict__ Wv,
    unsigned short* __restrict__ WF, unsigned* __restrict__ PM)
{
    const int tid = threadIdx.x;
    const int blk = blockIdx.x;
    if (blk < 512) {
        const int gid  = blk * 4 + (tid >> 6);         // (qb32, kb)
        const int lane = tid & 63, quad = lane >> 4, c = lane & 15;
        const int qb = gid >> 5, kb = gid & 31;
        unsigned w = 0;
        #pragma unroll
        for (int mt = 0; mt < 2; ++mt) {
            const int q = qb * 32 + mt * 16 + c;
            #pragma unroll
            for (int i = 0; i < 4; ++i) {
                const int4 mm = *(const int4*)&mask[(size_t)q * SEQ + kb * 64 + quad * 16 + 4 * i];
                if (mm.x) w |= 1u << (mt * 16 + i * 4 + 0);
                if (mm.y) w |= 1u << (mt * 16 + i * 4 + 1);
                if (mm.z) w |= 1u << (mt * 16 + i * 4 + 2);
                if (mm.w) w |= 1u << (mt * 16 + i * 4 + 3);
            }
        }
        PM[(size_t)gid * 64 + lane] = w;
    } else {
        const int s2 = (blk - 512) * 256 + tid;        // 0 .. 18431
        const int chunk = s2 >> 6, l = s2 & 63;
        const int ntg = chunk / 24, r = chunk - ntg * 24;
        const int kc = r >> 1, h = r & 1;
        const int mat = ntg >> 2;
        const int col = (ntg & 3) * 16 + (l & 15);
        const int k0 = kc * 64 + h * 32 + (l >> 4) * 8;
        const float* Wm = (mat == 0) ? Wq : (mat == 1) ? Wk : Wv;
        float p[8];
        #pragma unroll
        for (int j = 0; j < 8; ++j) p[j] = Wm[(size_t)(k0 + j) * 64 + col];
        uint4 w;
        w.x = packRNE(p[0], p[1]); w.y = packRNE(p[2], p[3]);
        w.z = packRNE(p[4], p[5]); w.w = packRNE(p[6], p[7]);
        *(uint4*)&WF[(size_t)s2 * 8] = w;
    }
}

// ---------------------------------------------------------------------------
// proj (verified R10 staged kernel + XCD-local block mapping, as R15/R17):
// block p handles batch b = p&7, row-tile t = p>>3 -> producer XCD ==
// consumer XCD for QF/KF/VF.  B staged via async global_load_lds from the
// WF intermediate (R19's register-staged-B variant spilled to scratch:
// 328MB WRITE_SIZE -- do NOT fuse B conversion into this pipeline).
// ---------------------------------------------------------------------------
__global__ __launch_bounds__(512, 4) void qkv_proj_kernel(
    const float* __restrict__ x, const unsigned short* __restrict__ WF,
    const float* __restrict__ bq, const float* __restrict__ bk, const float* __restrict__ bv,
    unsigned short* __restrict__ QF, unsigned short* __restrict__ KF,
    unsigned short* __restrict__ VF)
{
    __shared__ unsigned short AB[2][16384];   // per buf: A shorts [0,4096), B [4096,16384)
    unsigned short (*St)[200] = (unsigned short(*)[200])AB;   // epilogue overlay (25.6KB, buf0)

    const int tid = threadIdx.x;
    const int wv = tid >> 6, lane = tid & 63, quad = lane >> 4, c = lane & 15;
    const int rg = wv >> 2, cg = wv & 3;
    const int blk = blockIdx.x;
    const int bsw = blk & 7, tsw = blk >> 3;   // batch, row-tile (XCD-local)
    const int kbt = bsw * 32 + tsw;            // KV tile index == old blk role
    const int g0  = kbt * 4;                   // first rowgrp of block

    float bias[3];
    #pragma unroll
    for (int nt = 0; nt < 3; ++nt) {
        int col = cg * 48 + nt * 16 + c;
        const float* B = (col < 64) ? bq : (col < 128) ? bk : bv;
        bias[nt] = B[col & 63];
    }

    // A staging geometry: thread -> chunk (gl,h), frag lane l.  LDS word
    // tid*8 == chunk*512 + l*8 (frag-tiled image).
    const int chunk = tid >> 6;                // 0..7
    const int gl = chunk >> 1, hh = chunk & 1;
    const int arow = (g0 + gl) * 16 + (lane & 15);
    const float* xrow = x + (size_t)arow * WID + hh * 32 + ((lane >> 4) & 3) * 8;

    auto issueB = [&](int kc, int b) {
        #pragma unroll
        for (int r = 0; r < 3; ++r) {
            const int e = wv * 3 + r;          // 0..23: ntg = e>>1, half h
            const int ntg = e >> 1, h = e & 1;
            async16(WF + (((size_t)ntg * 12 + kc) * 2 + h) * 512 + lane * 8,
                    &AB[b][4096 + (ntg * 2 + h) * 512]);
        }
    };
    auto stageA_write = [&](int b, float4 f0, float4 f1) {
        uint4 w;
        w.x = packRNE(f0.x, f0.y); w.y = packRNE(f0.z, f0.w);
        w.z = packRNE(f1.x, f1.y); w.w = packRNE(f1.z, f1.w);
        *(uint4*)&AB[b][(size_t)tid * 8] = w;
    };

    f32x4 acc[2][3];
    #pragma unroll
    for (int mt = 0; mt < 2; ++mt)
        #pragma unroll
        for (int nt = 0; nt < 3; ++nt) acc[mt][nt] = zero4();

    {   // prologue: stage A(0) -> buf0, issue B(0) -> buf0
        float4 f0 = *(const float4*)&xrow[0];
        float4 f1 = *(const float4*)&xrow[4];
        stageA_write(0, f0, f1);
        issueB(0, 0);
    }

    for (int kc = 0; kc < 12; ++kc) {
        const int b = kc & 1;
        __syncthreads();   // publish buf b (B-DMA vmcnt + A ds_writes); b^1 readers done
        float4 f0, f1;
        if (kc < 11) {
            f0 = *(const float4*)&xrow[(kc + 1) * 64];
            f1 = *(const float4*)&xrow[(kc + 1) * 64 + 4];
            issueB(kc + 1, b ^ 1);
        }

        s8v afr[2][2], bfr[3][2];
        #pragma unroll
        for (int mt = 0; mt < 2; ++mt)
            #pragma unroll
            for (int h = 0; h < 2; ++h)
                afr[mt][h] = *(const s8v*)&AB[b][((rg * 2 + mt) * 2 + h) * 512 + lane * 8];
        #pragma unroll
        for (int nt = 0; nt < 3; ++nt)
            #pragma unroll
            for (int h = 0; h < 2; ++h)
                bfr[nt][h] = *(const s8v*)&AB[b][4096 + ((cg * 3 + nt) * 2 + h) * 512 + lane * 8];
        #pragma unroll
        for (int h = 0; h < 2; ++h)
            #pragma unroll
            for (int mt = 0; mt < 2; ++mt)
                #pragma unroll
                for (int nt = 0; nt < 3; ++nt)
                    acc[mt][nt] = __builtin_amdgcn_mfma_f32_16x16x32_bf16(
                        afr[mt][h], bfr[nt][h], acc[mt][nt], 0, 0, 0);

        if (kc < 11) stageA_write(b ^ 1, f0, f1);
    }

    // ---- epilogue: bias + stage 64x192 bf16 tile (overlays buf0)
    #pragma unroll
    for (int mt = 0; mt < 2; ++mt)
        #pragma unroll
        for (int nt = 0; nt < 3; ++nt)
            #pragma unroll
            for (int i = 0; i < 4; ++i)
                St[rg * 32 + mt * 16 + quad * 4 + i][cg * 48 + nt * 16 + c]
                    = f2b(acc[mt][nt][i] + bias[nt]);
    __syncthreads();

    {   // QF: rowgrp g = tid>>7, ks = (tid>>6)&1, frag lane l = tid&63
        const int g = tid >> 7, ks = (tid >> 6) & 1, l = tid & 63;
        uint4 v = *(uint4*)&St[g * 16 + (l & 15)][ks * 32 + (l >> 4) * 8];
        *(uint4*)&QF[(((size_t)(g0 + g)) * 2 + ks) * 512 + (size_t)l * 8] = v;
    }
    {   // KF: chunk ksnt = tid>>6 (ks = ksnt>>2, nt = ksnt&3), lane l
        const int ksnt = tid >> 6, l = tid & 63;
        const int ks = ksnt >> 2, nt = ksnt & 3;
        uint4 v = *(uint4*)&St[4 * (l & 15) + nt][64 + ks * 32 + (l >> 4) * 8];
        *(uint4*)&KF[(((size_t)kbt * 8 + ksnt) * 64 + l) * 8] = v;
    }
    {   // VF: chunk ksnt, lane l: gather St columns (V transpose), permuted
        // key axis: lane (quad,c) holds keys quad*16 + ks*8 + s  (s=0..7)
        const int ksnt = tid >> 6, l = tid & 63;
        const int ks = ksnt >> 2, nt = ksnt & 3;
        const int d = 128 + nt * 16 + (l & 15);
        const int r0 = (l >> 4) * 16 + ks * 8;
        unsigned short p[8];
        #pragma unroll
        for (int s = 0; s < 8; ++s) p[s] = St[r0 + s][d];
        uint4 w;
        w.x = (unsigned)p[0] | ((unsigned)p[1] << 16);
        w.y = (unsigned)p[2] | ((unsigned)p[3] << 16);
        w.z = (unsigned)p[4] | ((unsigned)p[5] << 16);
        w.w = (unsigned)p[6] | ((unsigned)p[7] << 16);
        *(uint4*)&VF[(((size_t)kbt * 8 + ksnt) * 64 + l) * 8] = w;
    }
}

// ---------------------------------------------------------------------------
// attn (verbatim R17, verified 47.0us, FROZEN): R12 geometry + batched loads
// with counted vmcnt + asm pins + raw v_exp_f32.  10 structural variants
// (staging, double-buffer, barrier-free, locality, occupancy, MLP) all land
// at 46-47us -- wall time is insensitive to in-kernel resources.
// ---------------------------------------------------------------------------
__global__ __launch_bounds__(1024, 4) void attn_kernel(
    const unsigned short* __restrict__ QF, const unsigned short* __restrict__ KF,
    const unsigned short* __restrict__ VF, const unsigned* __restrict__ PM,
    float* __restrict__ out)
{
    __shared__ float Obuf[64][68];             // 17.4KB merge buffer
    __shared__ float Lbuf[64];

    const int tid = threadIdx.x;
    const int wv = tid >> 6, lane = tid & 63, quad = lane >> 4, c = lane & 15;
    const int sl = wv & 3, qg = wv >> 2, mt = qg & 1;
    const int blk = blockIdx.x;
    const int bb = blk & 7, qt = blk >> 3;
    const size_t qrow0 = (size_t)bb * SEQ + qt * 64;

    if (tid < 64) Lbuf[tid] = 0.f;

    union Q8 { s8v v; unsigned w[4]; };
    Q8 qf[2];
    {
        const size_t qgrp = (size_t)bb * 128 + qt * 4 + qg;
        #pragma unroll
        for (int ks = 0; ks < 2; ++ks)
            qf[ks].v = *(const s8v*)&QF[(qgrp * 2 + ks) * 512 + (size_t)lane * 8];
    }

    f32x4 O[4];
    float lro0 = 0.f, lro1 = 0.f;
    #pragma unroll
    for (int nt = 0; nt < 4; ++nt) O[nt] = zero4();

    const unsigned* pmrow = PM + (size_t)((qt * 2 + (qg >> 1)) * 32 + sl * 8) * 64 + lane;

    #pragma unroll 1
    for (int kt = 0; kt < 8; ++kt) {
        const size_t kbg = (size_t)bb * 32 + sl * 8 + kt;
        const unsigned short* kb_ = KF + kbg * 4096 + (size_t)lane * 8;
        const unsigned short* vb_ = VF + kbg * 4096 + (size_t)lane * 8;

        const unsigned pmw = pmrow[(size_t)kt * 64];   // oldest outstanding

        // ---- issue ALL 16 fragment loads back-to-back (K first, V second)
        Q8 kf8[8], vf8[8];
        #pragma unroll
        for (int d = 0; d < 8; ++d) kf8[d].v = *(const s8v*)&kb_[(size_t)d * 512];
        #pragma unroll
        for (int d = 0; d < 8; ++d) vf8[d].v = *(const s8v*)&vb_[(size_t)d * 512];

        // ---- K (and pm) complete; V's 8 loads still in flight
        asm volatile("s_waitcnt vmcnt(8)" ::: "memory");
        #pragma unroll
        for (int d = 0; d < 8; ++d)
            #pragma unroll
            for (int j = 0; j < 4; ++j) asm volatile("" : "+v"(kf8[d].w[j]));
        __builtin_amdgcn_sched_barrier(0);

        // ---- S^T = K Q^T : lane (quad,c) gets S[q=c][key = 16*quad + 4*i + nt]
        f32x4 S[4];
        #pragma unroll
        for (int nt = 0; nt < 4; ++nt) S[nt] = zero4();
        #pragma unroll
        for (int ks = 0; ks < 2; ++ks)
            #pragma unroll
            for (int nt = 0; nt < 4; ++nt)
                S[nt] = __builtin_amdgcn_mfma_f32_16x16x32_bf16(kf8[ks * 4 + nt].v, qf[ks].v, S[nt], 0, 0, 0);

        // ---- fixed-shift softmax (raw v_exp_f32); V latency hides under this
        const unsigned pmh = pmw >> (mt * 16);
        float p[4][4];                              // p[nt][i] = key 16*quad+4*i+nt
        #pragma unroll
        for (int i = 0; i < 4; ++i)
            #pragma unroll
            for (int nt = 0; nt < 4; ++nt) {
                float e = __builtin_amdgcn_exp2f(
                    fmaf(S[nt][i], 0.18033688011112042f, -21.640425613334451f));
                p[nt][i] = ((pmh >> (i * 4 + nt)) & 1u) ? e : 0.f;
            }
        union { unsigned w[8]; s8v v[2]; } P;       // shorts = keys 16*quad+0..15
        #pragma unroll
        for (int j = 0; j < 8; ++j) {
            unsigned uu = packTRUNC(p[2 * (j & 1)][j >> 1], p[2 * (j & 1) + 1][j >> 1]);
            P.w[j] = uu;
            if (j & 1) lro1 += bitsf(uu << 16) + bitsf(uu & 0xFFFF0000u);
            else       lro0 += bitsf(uu << 16) + bitsf(uu & 0xFFFF0000u);
        }

        // ---- V complete; pin and run PV
        asm volatile("s_waitcnt vmcnt(0)" ::: "memory");
        #pragma unroll
        for (int d = 0; d < 8; ++d)
            #pragma unroll
            for (int j = 0; j < 4; ++j) asm volatile("" : "+v"(vf8[d].w[j]));
        __builtin_amdgcn_sched_barrier(0);

        #pragma unroll
        for (int ks = 0; ks < 2; ++ks)
            #pragma unroll
            for (int nt = 0; nt < 4; ++nt)
                O[nt] = __builtin_amdgcn_mfma_f32_16x16x32_bf16(P.v[ks], vf8[ks * 4 + nt].v, O[nt], 0, 0, 0);
    }

    // ---- merge 4 slices per q-group
    #pragma unroll
    for (int j = 0; j < 5; ++j) {
        int idx = tid + 1024 * j;
        if (idx < 64 * 68) ((float*)Obuf)[idx] = 0.f;
    }
    __syncthreads();

    {
        float l = lro0 + lro1;
        l += __shfl_xor(l, 16);
        l += __shfl_xor(l, 32);
        if (quad == 0) atomicAdd(&Lbuf[qg * 16 + c], l);
    }
    #pragma unroll
    for (int i = 0; i < 4; ++i)
        #pragma unroll
        for (int nt = 0; nt < 4; ++nt)
            atomicAdd(&Obuf[qg * 16 + quad * 4 + i][nt * 16 + c], O[nt][i]);
    __syncthreads();
    {
        const int r = tid >> 4, d4 = (tid & 15) * 4;
        const float invL = 1.0f / Lbuf[r];
        float4 v = *(float4*)&Obuf[r][d4];
        float4 o = make_float4(v.x * invL, v.y * invL, v.z * invL, v.w * invL);
        *(float4*)&out[(qrow0 + r) * 64 + d4] = o;
    }
}

extern "C" void kernel_launch(void* const* d_in, const int* in_sizes, int n_in,
                              void* d_out, int out_size, void* d_ws, size_t ws_size,
                              hipStream_t stream)
{
    const float* x    = (const float*)d_in[0];
    const float* Wq   = (const float*)d_in[1];
    const float* bq   = (const float*)d_in[2];
    const float* Wk   = (const float*)d_in[3];
    const float* bk   = (const float*)d_in[4];
    const float* Wv   = (const float*)d_in[5];
    const float* bv   = (const float*)d_in[6];
    const int*   mask = (const int*)d_in[7];
    float* out = (float*)d_out;

    // ws: QF/KF/VF 2MB each + WF 288KB + PM 512KB
    unsigned short* QF = (unsigned short*)d_ws;
    unsigned short* KF = QF + (size_t)16384 * 64;
    unsigned short* VF = KF + (size_t)16384 * 64;
    unsigned short* WF = VF + (size_t)16384 * 64;
    unsigned*       PM = (unsigned*)(WF + (size_t)192 * WID);

    convert_kernel<<<584, 256, 0, stream>>>(mask, Wq, Wk, Wv, WF, PM);
    qkv_proj_kernel<<<256, 512, 0, stream>>>(x, WF, bq, bk, bv, QF, KF, VF);
    attn_kernel<<<256, 1024, 0, stream>>>(QF, KF, VF, PM, out);
}

// Round 13
// 159.488 us; speedup vs baseline: 2.0419x; 1.0025x over previous
//
#include <hip/hip_runtime.h>

typedef short  s8v   __attribute__((ext_vector_type(8)));
typedef float  f32x4 __attribute__((ext_vector_type(4)));

#define SEQ 2048
#define WID 768

__device__ __forceinline__ unsigned fbits(float f) {
    union { float f; unsigned u; } v; v.f = f; return v.u;
}
__device__ __forceinline__ float bitsf(unsigned u) {
    union { unsigned u; float f; } v; v.u = u; return v.f;
}
__device__ __forceinline__ unsigned short f2b(float f) {
    unsigned u = fbits(f);
    return (unsigned short)((u + 0x7FFFu + ((u >> 16) & 1u)) >> 16);   // RNE
}
__device__ __forceinline__ unsigned packRNE(float a, float b) {
    unsigned ta = fbits(a) + 0x7FFFu + ((fbits(a) >> 16) & 1u);
    unsigned tb = fbits(b) + 0x7FFFu + ((fbits(b) >> 16) & 1u);
    return __builtin_amdgcn_perm(tb, ta, 0x07060302u);
}
__device__ __forceinline__ unsigned packTRUNC(float a, float b) {
    return __builtin_amdgcn_perm(fbits(b), fbits(a), 0x07060302u);
}
__device__ __forceinline__ f32x4 zero4() { f32x4 z = {0.f, 0.f, 0.f, 0.f}; return z; }

// async global->LDS DMA, 16B/lane; global ptr includes lane offset, LDS base wave-uniform
__device__ __forceinline__ void async16(const unsigned short* g, unsigned short* l) {
    __builtin_amdgcn_global_load_lds(
        (const __attribute__((address_space(1))) unsigned int*)g,
        (__attribute__((address_space(3))) unsigned int*)l, 16, 0, 0);
}

// ---------------------------------------------------------------------------
// convert_w: W -> WF bf16 B-frag-tiled (verified R10 logic, now standalone:
// the mask->PM half moved into the proj launch to overlap with proj).
// 72 blocks x 256 thr.
// ---------------------------------------------------------------------------
__global__ __launch_bounds__(256) void convert_w_kernel(
    const float* __restrict__ Wq, const float* __restrict__ Wk, const float* __restrict__ Wv,
    unsigned short* __restrict__ WF)
{
    const int s2 = blockIdx.x * 256 + threadIdx.x;     // 0 .. 18431
    const int chunk = s2 >> 6, l = s2 & 63;
    const int ntg = chunk / 24, r = chunk - ntg * 24;
    const int kc = r >> 1, h = r & 1;
    const int mat = ntg >> 2;
    const int col = (ntg & 3) * 16 + (l & 15);
    const int k0 = kc * 64 + h * 32 + (l >> 4) * 8;
    const float* Wm = (mat == 0) ? Wq : (mat == 1) ? Wk : Wv;
    float p[8];
    #pragma unroll
    for (int j = 0; j < 8; ++j) p[j] = Wm[(size_t)(k0 + j) * 64 + col];
    uint4 w;
    w.x = packRNE(p[0], p[1]); w.y = packRNE(p[2], p[3]);
    w.z = packRNE(p[4], p[5]); w.w = packRNE(p[6], p[7]);
    *(uint4*)&WF[(size_t)s2 * 8] = w;
}

// ---------------------------------------------------------------------------
// pm_proj: 512 blocks x 512 thr.  blocks [0,256): mask -> PM (8 gids/block,
// verified R10/R19 logic) -- runs CONCURRENTLY with proj on spare CUs
// instead of serially before it (PM is consumed only by attn).
// blocks [256,512): proj, verbatim R20-verified staged kernel (B via WF
// global_load_lds -- NOT register-staged, per R19's 328MB-spill lesson).
// XCD-local mapping preserved: p = blk-256, 256%8==0 -> block runs on
// XCD p%8 == bsw, producer XCD == consumer XCD for QF/KF/VF.
// ---------------------------------------------------------------------------
__global__ __launch_bounds__(512, 4) void pm_proj_kernel(
    const float* __restrict__ x, const int* __restrict__ mask,
    const unsigned short* __restrict__ WF,
    const float* __restrict__ bq, const float* __restrict__ bk, const float* __restrict__ bv,
    unsigned short* __restrict__ QF, unsigned short* __restrict__ KF,
    unsigned short* __restrict__ VF, unsigned* __restrict__ PM)
{
    __shared__ unsigned short AB[2][16384];   // per buf: A shorts [0,4096), B [4096,16384)
    unsigned short (*St)[200] = (unsigned short(*)[200])AB;   // epilogue overlay (25.6KB, buf0)

    const int tid = threadIdx.x;
    const int wv = tid >> 6, lane = tid & 63, quad = lane >> 4, c = lane & 15;
    const int blk = blockIdx.x;

    if (blk < 256) {
        // ---- mask -> PM, swapped layout (verified): gid = (qb32, kb)
        const int gid = blk * 8 + wv;              // 0..2047
        const int qb = gid >> 5, kb = gid & 31;
        unsigned w = 0;
        #pragma unroll
        for (int mt = 0; mt < 2; ++mt) {
            const int q = qb * 32 + mt * 16 + c;
            #pragma unroll
            for (int i = 0; i < 4; ++i) {
                const int4 mm = *(const int4*)&mask[(size_t)q * SEQ + kb * 64 + quad * 16 + 4 * i];
                if (mm.x) w |= 1u << (mt * 16 + i * 4 + 0);
                if (mm.y) w |= 1u << (mt * 16 + i * 4 + 1);
                if (mm.z) w |= 1u << (mt * 16 + i * 4 + 2);
                if (mm.w) w |= 1u << (mt * 16 + i * 4 + 3);
            }
        }
        PM[(size_t)gid * 64 + lane] = w;
        return;
    }

    // ---- proj role (verbatim R20-verified)
    const int p = blk - 256;
    const int rg = wv >> 2, cg = wv & 3;
    const int bsw = p & 7, tsw = p >> 3;       // batch, row-tile (XCD-local)
    const int kbt = bsw * 32 + tsw;            // KV tile index
    const int g0  = kbt * 4;                   // first rowgrp of block

    float bias[3];
    #pragma unroll
    for (int nt = 0; nt < 3; ++nt) {
        int col = cg * 48 + nt * 16 + c;
        const float* B = (col < 64) ? bq : (col < 128) ? bk : bv;
        bias[nt] = B[col & 63];
    }

    // A staging geometry: thread -> chunk (gl,h), frag lane l.  LDS word
    // tid*8 == chunk*512 + l*8 (frag-tiled image).
    const int chunk = tid >> 6;                // 0..7
    const int gl = chunk >> 1, hh = chunk & 1;
    const int arow = (g0 + gl) * 16 + (lane & 15);
    const float* xrow = x + (size_t)arow * WID + hh * 32 + ((lane >> 4) & 3) * 8;

    auto issueB = [&](int kc, int b) {
        #pragma unroll
        for (int r = 0; r < 3; ++r) {
            const int e = wv * 3 + r;          // 0..23: ntg = e>>1, half h
            const int ntg = e >> 1, h = e & 1;
            async16(WF + (((size_t)ntg * 12 + kc) * 2 + h) * 512 + lane * 8,
                    &AB[b][4096 + (ntg * 2 + h) * 512]);
        }
    };
    auto stageA_write = [&](int b, float4 f0, float4 f1) {
        uint4 w;
        w.x = packRNE(f0.x, f0.y); w.y = packRNE(f0.z, f0.w);
        w.z = packRNE(f1.x, f1.y); w.w = packRNE(f1.z, f1.w);
        *(uint4*)&AB[b][(size_t)tid * 8] = w;
    };

    f32x4 acc[2][3];
    #pragma unroll
    for (int mt = 0; mt < 2; ++mt)
        #pragma unroll
        for (int nt = 0; nt < 3; ++nt) acc[mt][nt] = zero4();

    {   // prologue: stage A(0) -> buf0, issue B(0) -> buf0
        float4 f0 = *(const float4*)&xrow[0];
        float4 f1 = *(const float4*)&xrow[4];
        stageA_write(0, f0, f1);
        issueB(0, 0);
    }

    for (int kc = 0; kc < 12; ++kc) {
        const int b = kc & 1;
        __syncthreads();   // publish buf b (B-DMA vmcnt + A ds_writes); b^1 readers done
        float4 f0, f1;
        if (kc < 11) {
            f0 = *(const float4*)&xrow[(kc + 1) * 64];
            f1 = *(const float4*)&xrow[(kc + 1) * 64 + 4];
            issueB(kc + 1, b ^ 1);
        }

        s8v afr[2][2], bfr[3][2];
        #pragma unroll
        for (int mt = 0; mt < 2; ++mt)
            #pragma unroll
            for (int h = 0; h < 2; ++h)
                afr[mt][h] = *(const s8v*)&AB[b][((rg * 2 + mt) * 2 + h) * 512 + lane * 8];
        #pragma unroll
        for (int nt = 0; nt < 3; ++nt)
            #pragma unroll
            for (int h = 0; h < 2; ++h)
                bfr[nt][h] = *(const s8v*)&AB[b][4096 + ((cg * 3 + nt) * 2 + h) * 512 + lane * 8];
        #pragma unroll
        for (int h = 0; h < 2; ++h)
            #pragma unroll
            for (int mt = 0; mt < 2; ++mt)
                #pragma unroll
                for (int nt = 0; nt < 3; ++nt)
                    acc[mt][nt] = __builtin_amdgcn_mfma_f32_16x16x32_bf16(
                        afr[mt][h], bfr[nt][h], acc[mt][nt], 0, 0, 0);

        if (kc < 11) stageA_write(b ^ 1, f0, f1);
    }

    // ---- epilogue: bias + stage 64x192 bf16 tile (overlays buf0)
    #pragma unroll
    for (int mt = 0; mt < 2; ++mt)
        #pragma unroll
        for (int nt = 0; nt < 3; ++nt)
            #pragma unroll
            for (int i = 0; i < 4; ++i)
                St[rg * 32 + mt * 16 + quad * 4 + i][cg * 48 + nt * 16 + c]
                    = f2b(acc[mt][nt][i] + bias[nt]);
    __syncthreads();

    {   // QF: rowgrp g = tid>>7, ks = (tid>>6)&1, frag lane l = tid&63
        const int g = tid >> 7, ks = (tid >> 6) & 1, l = tid & 63;
        uint4 v = *(uint4*)&St[g * 16 + (l & 15)][ks * 32 + (l >> 4) * 8];
        *(uint4*)&QF[(((size_t)(g0 + g)) * 2 + ks) * 512 + (size_t)l * 8] = v;
    }
    {   // KF: chunk ksnt = tid>>6 (ks = ksnt>>2, nt = ksnt&3), lane l
        const int ksnt = tid >> 6, l = tid & 63;
        const int ks = ksnt >> 2, nt = ksnt & 3;
        uint4 v = *(uint4*)&St[4 * (l & 15) + nt][64 + ks * 32 + (l >> 4) * 8];
        *(uint4*)&KF[(((size_t)kbt * 8 + ksnt) * 64 + l) * 8] = v;
    }
    {   // VF: chunk ksnt, lane l: gather St columns (V transpose), permuted
        // key axis: lane (quad,c) holds keys quad*16 + ks*8 + s  (s=0..7)
        const int ksnt = tid >> 6, l = tid & 63;
        const int ks = ksnt >> 2, nt = ksnt & 3;
        const int d = 128 + nt * 16 + (l & 15);
        const int r0 = (l >> 4) * 16 + ks * 8;
        unsigned short pp[8];
        #pragma unroll
        for (int s = 0; s < 8; ++s) pp[s] = St[r0 + s][d];
        uint4 w;
        w.x = (unsigned)pp[0] | ((unsigned)pp[1] << 16);
        w.y = (unsigned)pp[2] | ((unsigned)pp[3] << 16);
        w.z = (unsigned)pp[4] | ((unsigned)pp[5] << 16);
        w.w = (unsigned)pp[6] | ((unsigned)pp[7] << 16);
        *(uint4*)&VF[(((size_t)kbt * 8 + ksnt) * 64 + l) * 8] = w;
    }
}

// ---------------------------------------------------------------------------
// attn (verbatim R17, verified 46.5us, FROZEN): R12 geometry + batched loads
// with counted vmcnt + asm pins + raw v_exp_f32.  10 structural variants
// (staging, double-buffer, barrier-free, locality, occupancy, MLP) all land
// at 46-47us -- wall time is insensitive to in-kernel resources.
// ---------------------------------------------------------------------------
__global__ __launch_bounds__(1024, 4) void attn_kernel(
    const unsigned short* __restrict__ QF, const unsigned short* __restrict__ KF,
    const unsigned short* __restrict__ VF, const unsigned* __restrict__ PM,
    float* __restrict__ out)
{
    __shared__ float Obuf[64][68];             // 17.4KB merge buffer
    __shared__ float Lbuf[64];

    const int tid = threadIdx.x;
    const int wv = tid >> 6, lane = tid & 63, quad = lane >> 4, c = lane & 15;
    const int sl = wv & 3, qg = wv >> 2, mt = qg & 1;
    const int blk = blockIdx.x;
    const int bb = blk & 7, qt = blk >> 3;
    const size_t qrow0 = (size_t)bb * SEQ + qt * 64;

    if (tid < 64) Lbuf[tid] = 0.f;

    union Q8 { s8v v; unsigned w[4]; };
    Q8 qf[2];
    {
        const size_t qgrp = (size_t)bb * 128 + qt * 4 + qg;
        #pragma unroll
        for (int ks = 0; ks < 2; ++ks)
            qf[ks].v = *(const s8v*)&QF[(qgrp * 2 + ks) * 512 + (size_t)lane * 8];
    }

    f32x4 O[4];
    float lro0 = 0.f, lro1 = 0.f;
    #pragma unroll
    for (int nt = 0; nt < 4; ++nt) O[nt] = zero4();

    const unsigned* pmrow = PM + (size_t)((qt * 2 + (qg >> 1)) * 32 + sl * 8) * 64 + lane;

    #pragma unroll 1
    for (int kt = 0; kt < 8; ++kt) {
        const size_t kbg = (size_t)bb * 32 + sl * 8 + kt;
        const unsigned short* kb_ = KF + kbg * 4096 + (size_t)lane * 8;
        const unsigned short* vb_ = VF + kbg * 4096 + (size_t)lane * 8;

        const unsigned pmw = pmrow[(size_t)kt * 64];   // oldest outstanding

        // ---- issue ALL 16 fragment loads back-to-back (K first, V second)
        Q8 kf8[8], vf8[8];
        #pragma unroll
        for (int d = 0; d < 8; ++d) kf8[d].v = *(const s8v*)&kb_[(size_t)d * 512];
        #pragma unroll
        for (int d = 0; d < 8; ++d) vf8[d].v = *(const s8v*)&vb_[(size_t)d * 512];

        // ---- K (and pm) complete; V's 8 loads still in flight
        asm volatile("s_waitcnt vmcnt(8)" ::: "memory");
        #pragma unroll
        for (int d = 0; d < 8; ++d)
            #pragma unroll
            for (int j = 0; j < 4; ++j) asm volatile("" : "+v"(kf8[d].w[j]));
        __builtin_amdgcn_sched_barrier(0);

        // ---- S^T = K Q^T : lane (quad,c) gets S[q=c][key = 16*quad + 4*i + nt]
        f32x4 S[4];
        #pragma unroll
        for (int nt = 0; nt < 4; ++nt) S[nt] = zero4();
        #pragma unroll
        for (int ks = 0; ks < 2; ++ks)
            #pragma unroll
            for (int nt = 0; nt < 4; ++nt)
                S[nt] = __builtin_amdgcn_mfma_f32_16x16x32_bf16(kf8[ks * 4 + nt].v, qf[ks].v, S[nt], 0, 0, 0);

        // ---- fixed-shift softmax (raw v_exp_f32); V latency hides under this
        const unsigned pmh = pmw >> (mt * 16);
        float p[4][4];                              // p[nt][i] = key 16*quad+4*i+nt
        #pragma unroll
        for (int i = 0; i < 4; ++i)
            #pragma unroll
            for (int nt = 0; nt < 4; ++nt) {
                float e = __builtin_amdgcn_exp2f(
                    fmaf(S[nt][i], 0.18033688011112042f, -21.640425613334451f));
                p[nt][i] = ((pmh >> (i * 4 + nt)) & 1u) ? e : 0.f;
            }
        union { unsigned w[8]; s8v v[2]; } P;       // shorts = keys 16*quad+0..15
        #pragma unroll
        for (int j = 0; j < 8; ++j) {
            unsigned uu = packTRUNC(p[2 * (j & 1)][j >> 1], p[2 * (j & 1) + 1][j >> 1]);
            P.w[j] = uu;
            if (j & 1) lro1 += bitsf(uu << 16) + bitsf(uu & 0xFFFF0000u);
            else       lro0 += bitsf(uu << 16) + bitsf(uu & 0xFFFF0000u);
        }

        // ---- V complete; pin and run PV
        asm volatile("s_waitcnt vmcnt(0)" ::: "memory");
        #pragma unroll
        for (int d = 0; d < 8; ++d)
            #pragma unroll
            for (int j = 0; j < 4; ++j) asm volatile("" : "+v"(vf8[d].w[j]));
        __builtin_amdgcn_sched_barrier(0);

        #pragma unroll
        for (int ks = 0; ks < 2; ++ks)
            #pragma unroll
            for (int nt = 0; nt < 4; ++nt)
                O[nt] = __builtin_amdgcn_mfma_f32_16x16x32_bf16(P.v[ks], vf8[ks * 4 + nt].v, O[nt], 0, 0, 0);
    }

    // ---- merge 4 slices per q-group
    #pragma unroll
    for (int j = 0; j < 5; ++j) {
        int idx = tid + 1024 * j;
        if (idx < 64 * 68) ((float*)Obuf)[idx] = 0.f;
    }
    __syncthreads();

    {
        float l = lro0 + lro1;
        l += __shfl_xor(l, 16);
        l += __shfl_xor(l, 32);
        if (quad == 0) atomicAdd(&Lbuf[qg * 16 + c], l);
    }
    #pragma unroll
    for (int i = 0; i < 4; ++i)
        #pragma unroll
        for (int nt = 0; nt < 4; ++nt)
            atomicAdd(&Obuf[qg * 16 + quad * 4 + i][nt * 16 + c], O[nt][i]);
    __syncthreads();
    {
        const int r = tid >> 4, d4 = (tid & 15) * 4;
        const float invL = 1.0f / Lbuf[r];
        float4 v = *(float4*)&Obuf[r][d4];
        float4 o = make_float4(v.x * invL, v.y * invL, v.z * invL, v.w * invL);
        *(float4*)&out[(qrow0 + r) * 64 + d4] = o;
    }
}

extern "C" void kernel_launch(void* const* d_in, const int* in_sizes, int n_in,
                              void* d_out, int out_size, void* d_ws, size_t ws_size,
                              hipStream_t stream)
{
    const float* x    = (const float*)d_in[0];
    const float* Wq   = (const float*)d_in[1];
    const float* bq   = (const float*)d_in[2];
    const float* Wk   = (const float*)d_in[3];
    const float* bk   = (const float*)d_in[4];
    const float* Wv   = (const float*)d_in[5];
    const float* bv   = (const float*)d_in[6];
    const int*   mask = (const int*)d_in[7];
    float* out = (float*)d_out;

    // ws: QF/KF/VF 2MB each + WF 288KB + PM 512KB
    unsigned short* QF = (unsigned short*)d_ws;
    unsigned short* KF = QF + (size_t)16384 * 64;
    unsigned short* VF = KF + (size_t)16384 * 64;
    unsigned short* WF = VF + (size_t)16384 * 64;
    unsigned*       PM = (unsigned*)(WF + (size_t)192 * WID);

    convert_w_kernel<<<72, 256, 0, stream>>>(Wq, Wk, Wv, WF);
    pm_proj_kernel<<<512, 512, 0, stream>>>(x, mask, WF, bq, bk, bv, QF, KF, VF, PM);
    attn_kernel<<<256, 1024, 0, stream>>>(QF, KF, VF, PM, out);
}